// Round 5
// baseline (149.524 us; speedup 1.0000x reference)
//
#include <hip/hip_runtime.h>
#include <math.h>
#include <stdint.h>

#define LATN 721
#define LONN 1440
#define NLEV 13
#define NBATCH 2
#define SLICE (LATN * LONN)              // 1,038,240
#define BATSTRIDE (NLEV * SLICE)

// fused-tile geometry (TI=12: halo ratio 476/384=1.24)
#define TI 12
#define TJ 32
#define HR (TI + 2)                      // 14 halo rows
#define HC (TJ + 2)                      // 34 halo cols
#define HRHC (HR * HC)                   // 476
#define NPTS (TI * TJ)                   // 384 interior points
#define NRT 61                           // ceil(721/12)
#define NCT 45                           // 1440/32
#define NWG (NRT * NCT)                  // 2745

// fast-path pair decomposition: 18 col-pairs x 14 rows = 252 slots
#define NPR 18
#define NSLOT (HR * NPR)                 // 252

// ---- ws float layout ----
#define NBANK      128
#define BANKSTRIDE 64
#define WS_ACC     0                     // [NBANK*BANKSTRIDE]
#define ACC_SUM    0        // [26] per (b,l) sums
#define ACC_SSQ    26       // [2]  per-batch total sum-of-squares
#define ACC_GRAD   28
#define ACC_MASS   29
#define N_ACC      30
#define WS_INVDX   (NBANK * BANKSTRIDE)          // [721]
#define WS_FCOR    (WS_INVDX + LATN)             // [721]
#define WS_W       (WS_FCOR + LATN)              // [13]
#define WS_INVDP   (WS_W + NLEV)
#define WS_INV2DP  (WS_INVDP + 1)

constexpr float INV_R     = (float)(1.0 / 6371000.0);
constexpr float INV_DLAT  = (float)(720.0 / M_PI);
constexpr float INV_2DLAT = (float)(360.0 / M_PI);
constexpr float INV_DLON  = (float)(1440.0 / (2.0 * M_PI));
constexpr float INV_2DLON = (float)(720.0 / (2.0 * M_PI));
constexpr float QG_COEF   = 1e-4f;   // F0^2 / N^2

// ---------------- setup: row tables, weights, zero accumulators ----------------
__global__ void pl_setup_kernel(const float* __restrict__ plev, float* __restrict__ ws) {
    const int t = threadIdx.x;
    if (t < LATN) {
        double lat;
        if (t == 0)            lat = (double)(-(float)(M_PI / 2.0));
        else if (t == LATN-1)  lat = (double)( (float)(M_PI / 2.0));
        else                   lat = (double)((float)(-M_PI / 2.0 + (double)t * (M_PI / 720.0)));
        double c = cos(lat);
        if (c < 1e-8) c = 1e-8;                      // matches jnp.clip(cos, 1e-8)
        ws[WS_INVDX + t] = (float)(1.0 / (6371000.0 * c));
        ws[WS_FCOR  + t] = (float)(2.0 * 7.292e-05 * sin(lat));
    }
    if (t < NLEV) {
        float p[NLEV];
        #pragma unroll
        for (int l = 0; l < NLEV; ++l) p[l] = plev[l] * 100.0f;
        float dpl[NLEV-1];
        #pragma unroll
        for (int l = 0; l < NLEV-1; ++l) dpl[l] = p[l+1] - p[l];
        float raw;
        if (t == 0)            raw = dpl[0] * 0.5f;
        else if (t == NLEV-1)  raw = dpl[NLEV-2] * 0.5f;
        else                   raw = (dpl[t-1] + dpl[t]) * 0.5f;
        float s = dpl[0] * 0.5f + dpl[NLEV-2] * 0.5f;
        #pragma unroll
        for (int l = 1; l < NLEV-1; ++l) s += (dpl[l-1] + dpl[l]) * 0.5f;
        if (s < 1e-8f) s = 1e-8f;
        ws[WS_W + t] = raw / s;
    }
    if (t == 0) {
        float sd = 0.f;
        for (int l = 0; l < NLEV-1; ++l) sd += plev[l+1] - plev[l];
        float dp = sd / (float)(NLEV-1) * 100.0f;    // mean(diff)*100 (hPa->Pa)
        ws[WS_INVDP]  = 1.0f / dp;
        ws[WS_INV2DP] = 1.0f / (2.0f * dp);
    }
    for (int z = t; z < NBANK * BANKSTRIDE; z += 1024) ws[WS_ACC + z] = 0.0f;
}

// ---------------- helpers ----------------
__device__ __forceinline__ int swz_nwg(int orig, int nwg) {
    // bijective XCD-chunk swizzle (m204)
    const int q = nwg >> 3, r = nwg & 7;
    const int x = orig & 7, k = orig >> 3;
    return (x < r ? x * (q + 1) : r * (q + 1) + (x - r) * q) + k;
}

__device__ __forceinline__ float2 ld2(const float* p) {
    return *reinterpret_cast<const float2*>(p);
}

// vertical stencil + qg/Ucol/Vcol emission for one halo point (identical math all rounds)
__device__ __forceinline__ void emit_point(float* __restrict__ qg,
                                           float* __restrict__ Ucol, float* __restrict__ Vcol,
                                           int hidx, const float (&vo)[NLEV],
                                           float wu, float wv, float fc,
                                           float idp, float i2dp)
{
    Ucol[hidx] = wu;
    Vcol[hidx] = wv;
    float vp1m = (vo[1] - vo[0]) * idp;              // vp1[0]
    float vp1c = (vo[2] - vo[0]) * i2dp;             // vp1[1]
    qg[0 * HRHC + hidx] = vo[0] + fc + QG_COEF * ((vp1c - vp1m) * idp);
    #pragma unroll
    for (int l = 1; l < NLEV - 1; ++l) {
        const float vp1n = (l == NLEV - 2) ? (vo[NLEV-1] - vo[NLEV-2]) * idp
                                           : (vo[l+2] - vo[l]) * i2dp;   // vp1[l+1]
        qg[l * HRHC + hidx] = vo[l] + fc + QG_COEF * ((vp1n - vp1m) * i2dp);
        vp1m = vp1c; vp1c = vp1n;
    }
    qg[(NLEV-1) * HRHC + hidx] = vo[NLEV-1] + fc + QG_COEF * ((vp1c - vp1m) * idp);
}

// ---------------- fused kernel: register-gather phase 1 (no staging, no barriers) ----------------
__launch_bounds__(256, 4)
__global__ void pl_fused_kernel(const float* __restrict__ u, const float* __restrict__ v,
                                float* __restrict__ ws)
{
    __shared__ float qg[NLEV * HRHC];        // 24,752 B
    __shared__ float uvred[2 * HRHC];        // Ucol/Vcol; reused as red[16][16]
    float* Ucol = uvred;
    float* Vcol = uvred + HRHC;
    // total LDS = 28,560 B -> up to 5 WG/CU

    const int tid = threadIdx.x;
    const int b  = blockIdx.y;
    const int wg = swz_nwg(blockIdx.x, NWG);
    const int rt = wg / NCT, ct = wg - rt * NCT;
    const int i0 = rt * TI, j0 = ct * TJ;

    const float* ub = u + (size_t)b * BATSTRIDE;
    const float* vb = v + (size_t)b * BATSTRIDE;
    const float idp = ws[WS_INVDP], i2dp = ws[WS_INV2DP];

    // fast path: tile needs rows i0-2..i0+13 and cols j0-4..j0+35 un-clamped
    const bool fastp = (rt >= 1) && (rt <= 58) && (ct >= 1) && (ct <= 43);

    if (fastp) {
        // ---- phase 1 fast: per-thread 2-col pair, 6 aligned float2 loads/level ----
        if (tid < NSLOT) {
            const int row = tid / NPR, k = tid - row * NPR;
            const int r  = i0 - 1 + row;            // halo row (interior: central diffs)
            const int ce = j0 - 2 + 2 * k;          // even base col of the pair
            const int o  = r * LONN + ce;           // element offset (8B-aligned)
            const float sr = INV_2DLAT * INV_R;
            const float sc = INV_2DLON * ws[WS_INVDX + r];
            const float fc = ws[WS_FCOR + r];

            float vo0[NLEV], vo1[NLEV];
            float wu0 = 0.f, wu1 = 0.f, wv0 = 0.f, wv1 = 0.f;
            const float* up = ub;
            const float* vp = vb;
            #pragma unroll
            for (int l = 0; l < NLEV; ++l) {
                const float wl = ws[WS_W + l];                   // uniform
                const float2 u_c = ld2(up + o);
                const float2 u_p = ld2(up + o + LONN);
                const float2 u_m = ld2(up + o - LONN);
                const float2 v_c = ld2(vp + o);
                const float2 v_l = ld2(vp + o - 2);
                const float2 v_r = ld2(vp + o + 2);
                // point0 = col ce:   dvdx = (v[ce+1]-v[ce-1])*sc ; dudy = (u_p-u_m).x*sr
                vo0[l] = (v_c.y - v_l.y) * sc - (u_p.x - u_m.x) * sr;
                // point1 = col ce+1: dvdx = (v[ce+2]-v[ce])*sc
                vo1[l] = (v_r.x - v_c.x) * sc - (u_p.y - u_m.y) * sr;
                wu0 = fmaf(wl, u_c.x, wu0);  wu1 = fmaf(wl, u_c.y, wu1);
                wv0 = fmaf(wl, v_c.x, wv0);  wv1 = fmaf(wl, v_c.y, wv1);
                up += SLICE; vp += SLICE;                        // SALU bump
            }
            // point0 is halo col hc=2k-1 (valid k>=1); point1 is hc=2k (valid k<=16)
            if (k >= 1)
                emit_point(qg, Ucol, Vcol, row * HC + 2 * k - 1, vo0, wu0, wv0, fc, idp, i2dp);
            if (k <= NPR - 2)
                emit_point(qg, Ucol, Vcol, row * HC + 2 * k,     vo1, wu1, wv1, fc, idp, i2dp);
        }
    } else {
        // ---- phase 1 slow (edge tiles, ~9% of WGs): R3's clamped scalar gathers ----
        for (int hidx = tid; hidx < HRHC; hidx += 256) {
            const int hr = hidx / HC, hc = hidx - hr * HC;
            const int r = max(0, min(i0 - 1 + hr, LATN - 1));
            const int c = max(0, min(j0 - 1 + hc, LONN - 1));
            const int occ = r * LONN + c;
            const int ocp = r * LONN + min(c + 1, LONN - 1);
            const int ocm = r * LONN + max(c - 1, 0);
            const int opc = min(r + 1, LATN - 1) * LONN + c;
            const int omc = max(r - 1, 0) * LONN + c;
            const float sc = ((c == 0 || c == LONN - 1) ? INV_DLON : INV_2DLON) * ws[WS_INVDX + r];
            const float sr = ((r == 0 || r == LATN - 1) ? INV_DLAT : INV_2DLAT) * INV_R;
            const float fc = ws[WS_FCOR + r];

            float vo[NLEV];
            float wu = 0.f, wv = 0.f;
            const float* up = ub;
            const float* vp = vb;
            #pragma unroll
            for (int l = 0; l < NLEV; ++l) {
                const float wl = ws[WS_W + l];
                vo[l] = (vp[ocp] - vp[ocm]) * sc - (up[opc] - up[omc]) * sr;
                wu = fmaf(wl, up[occ], wu);
                wv = fmaf(wl, vp[occ], wv);
                up += SLICE; vp += SLICE;
            }
            emit_point(qg, Ucol, Vcol, hidx, vo, wu, wv, fc, idp, i2dp);
        }
    }
    __syncthreads();

    // ---- phase 2: pure-LDS stencils over 384 interior points ----
    float vals[16];
    #pragma unroll
    for (int k = 0; k < 16; ++k) vals[k] = 0.f;

    for (int p = tid; p < NPTS; p += 256) {
        const int oi = p >> 5, oj = p & 31;
        const int i = i0 + oi, j = j0 + oj;
        const float mval = (i < LATN) ? 1.f : 0.f;
        const int ic = min(i, LATN - 1);
        const int hb = (oi + 1) * HC + (oj + 1);
        const float siR = ((ic == 0 || ic == LATN - 1) ? INV_DLAT : INV_2DLAT) * INV_R;
        const float sjx = ((j == 0 || j == LONN - 1) ? INV_DLON : INV_2DLON) * ws[WS_INVDX + ic];

        float ssqt = 0.f, grad = 0.f;
        #pragma unroll
        for (int l = 0; l < NLEV; ++l) {
            const int base = l * HRHC + hb;
            const float qc = qg[base] * mval;            // masked at source
            const float gl = (qg[base + HC] - qg[base - HC]) * siR;
            const float gn = (qg[base + 1]  - qg[base - 1])  * sjx;
            vals[l] += qc;
            ssqt += qc * qc;
            grad += gl * gl + gn * gn;
        }
        const float du = (Ucol[hb + 1]  - Ucol[hb - 1])  * sjx;
        const float dv = (Vcol[hb + HC] - Vcol[hb - HC]) * siR;
        const float cd = du + dv;
        vals[13] += ssqt;
        vals[14] = fmaf(mval, grad, vals[14]);
        vals[15] = fmaf(mval, cd * cd, vals[15]);
    }

    // ---- reduction: 4-step 16-lane-group butterfly + LDS transpose ----
    #pragma unroll
    for (int k = 0; k < 16; ++k) {
        float x = vals[k];
        x += __shfl_xor(x, 8, 64);
        x += __shfl_xor(x, 4, 64);
        x += __shfl_xor(x, 2, 64);
        x += __shfl_xor(x, 1, 64);
        vals[k] = x;
    }
    const int g = tid >> 4, k16 = tid & 15;
    float myv = vals[0];
    #pragma unroll
    for (int k = 1; k < 16; ++k) if (k16 == k) myv = vals[k];   // static-index select

    __syncthreads();                         // Ucol/Vcol reads done -> reuse as red
    float (*red)[16] = (float (*)[16])uvred;
    red[g][k16] = myv;
    __syncthreads();

    if (tid < 16) {
        const int k = tid;
        float s = 0.f;
        #pragma unroll
        for (int g2 = 0; g2 < 16; ++g2) s += red[g2][k];
        int target;
        if (k < 13)       target = ACC_SUM + b * 13 + k;
        else if (k == 13) target = ACC_SSQ + b;
        else if (k == 14) target = ACC_GRAD;
        else              target = ACC_MASS;
        const int bank = (b * NWG + blockIdx.x) & (NBANK - 1);
        atomicAdd(&ws[WS_ACC + bank * BANKSTRIDE + target], s);
    }
}

// ---------------- finalize: sum banks, apply formulas ----------------
__global__ void pl_finalize_kernel(const float* __restrict__ ws, float* __restrict__ out) {
    __shared__ float tot[N_ACC];
    const int t = threadIdx.x;
    if (t < N_ACC) {
        float s = 0.f;
        for (int bk = 0; bk < NBANK; ++bk) s += ws[WS_ACC + bk * BANKSTRIDE + t];
        tot[t] = s;
    }
    __syncthreads();
    if (t == 0) {
        const float N = (float)SLICE;
        float s2 = 0.f;
        for (int s = 0; s < 2 * NLEV; ++s) s2 += tot[ACC_SUM + s] * tot[ACC_SUM + s];
        const float ssq = tot[ACC_SSQ + 0] + tot[ACC_SSQ + 1];
        float vmean = (ssq - s2 / N) / (N - 1.0f) * (1.0f / (2.0f * NLEV));
        float gmean = tot[ACC_GRAD] / (float)(NBATCH * NLEV * SLICE);
        float mmean = tot[ACC_MASS] / (float)(NBATCH * SLICE);
        out[0] = vmean + 0.1f * gmean + mmean;          // spectra_loss statically 0
    }
}

extern "C" void kernel_launch(void* const* d_in, const int* in_sizes, int n_in,
                              void* d_out, int out_size, void* d_ws, size_t ws_size,
                              hipStream_t stream) {
    const float* u    = (const float*)d_in[0];
    const float* v    = (const float*)d_in[1];
    const float* plev = (const float*)d_in[2];
    float* ws  = (float*)d_ws;
    float* out = (float*)d_out;

    hipLaunchKernelGGL(pl_setup_kernel, dim3(1), dim3(1024), 0, stream, plev, ws);
    hipLaunchKernelGGL(pl_fused_kernel, dim3(NWG, NBATCH), dim3(256), 0, stream, u, v, ws);
    hipLaunchKernelGGL(pl_finalize_kernel, dim3(1), dim3(64), 0, stream, ws, out);
}

// Round 6
// 98.123 us; speedup vs baseline: 1.5238x; 1.5238x over previous
//
#include <hip/hip_runtime.h>
#include <math.h>
#include <stdint.h>

#define LATN 721
#define LONN 1440
#define NLEV 13
#define NBATCH 2
#define SLICE (LATN * LONN)              // 1,038,240
#define BATSTRIDE (NLEV * SLICE)

// fused-tile geometry: TJ=30 -> HC=32 -> per-wave 4 halo rows = 128 pts = 2/lane exact
#define TI 12
#define TJ 30
#define HR (TI + 2)                      // 14 halo rows
#define HC (TJ + 2)                      // 32 halo cols
#define HRHC (HR * HC)                   // 448
#define NPTS (TI * TJ)                   // 360 interior points
#define NRT 61                           // ceil(721/12)
#define NCT 48                           // 1440/30
#define NWG (NRT * NCT)                  // 2928

// per-wave staging: u 6 rows + v 4 rows x 40 cols (10 float4 groups)
#define SCOLS 40
#define UROWS 6
#define VROWS 4
#define BUFFL 400                        // floats per level buffer (u 240 + v 160)
#define NRING 3                          // wave-private ring depth (d=2 prefetch safe)
#define WVFL (NRING * BUFFL)             // 1200 floats per wave

// ---- ws float layout ----
#define NBANK      128
#define BANKSTRIDE 64
#define WS_ACC     0                     // [NBANK*BANKSTRIDE]
#define ACC_SUM    0        // [26] per (b,l) sums
#define ACC_SSQ    26       // [2]  per-batch total sum-of-squares
#define ACC_GRAD   28
#define ACC_MASS   29
#define N_ACC      30
#define WS_INVDX   (NBANK * BANKSTRIDE)          // [721]
#define WS_FCOR    (WS_INVDX + LATN)             // [721]
#define WS_W       (WS_FCOR + LATN)              // [13]
#define WS_INVDP   (WS_W + NLEV)
#define WS_INV2DP  (WS_INVDP + 1)

constexpr float INV_R     = (float)(1.0 / 6371000.0);
constexpr float INV_DLAT  = (float)(720.0 / M_PI);
constexpr float INV_2DLAT = (float)(360.0 / M_PI);
constexpr float INV_DLON  = (float)(1440.0 / (2.0 * M_PI));
constexpr float INV_2DLON = (float)(720.0 / (2.0 * M_PI));
constexpr float QG_COEF   = 1e-4f;   // F0^2 / N^2

// ---------------- setup: row tables, weights, zero accumulators ----------------
__global__ void pl_setup_kernel(const float* __restrict__ plev, float* __restrict__ ws) {
    const int t = threadIdx.x;
    if (t < LATN) {
        double lat;
        if (t == 0)            lat = (double)(-(float)(M_PI / 2.0));
        else if (t == LATN-1)  lat = (double)( (float)(M_PI / 2.0));
        else                   lat = (double)((float)(-M_PI / 2.0 + (double)t * (M_PI / 720.0)));
        double c = cos(lat);
        if (c < 1e-8) c = 1e-8;                      // matches jnp.clip(cos, 1e-8)
        ws[WS_INVDX + t] = (float)(1.0 / (6371000.0 * c));
        ws[WS_FCOR  + t] = (float)(2.0 * 7.292e-05 * sin(lat));
    }
    if (t < NLEV) {
        float p[NLEV];
        #pragma unroll
        for (int l = 0; l < NLEV; ++l) p[l] = plev[l] * 100.0f;
        float dpl[NLEV-1];
        #pragma unroll
        for (int l = 0; l < NLEV-1; ++l) dpl[l] = p[l+1] - p[l];
        float raw;
        if (t == 0)            raw = dpl[0] * 0.5f;
        else if (t == NLEV-1)  raw = dpl[NLEV-2] * 0.5f;
        else                   raw = (dpl[t-1] + dpl[t]) * 0.5f;
        float s = dpl[0] * 0.5f + dpl[NLEV-2] * 0.5f;
        #pragma unroll
        for (int l = 1; l < NLEV-1; ++l) s += (dpl[l-1] + dpl[l]) * 0.5f;
        if (s < 1e-8f) s = 1e-8f;
        ws[WS_W + t] = raw / s;
    }
    if (t == 0) {
        float sd = 0.f;
        for (int l = 0; l < NLEV-1; ++l) sd += plev[l+1] - plev[l];
        float dp = sd / (float)(NLEV-1) * 100.0f;    // mean(diff)*100 (hPa->Pa)
        ws[WS_INVDP]  = 1.0f / dp;
        ws[WS_INV2DP] = 1.0f / (2.0f * dp);
    }
    for (int z = t; z < NBANK * BANKSTRIDE; z += 1024) ws[WS_ACC + z] = 0.0f;
}

// ---------------- helpers ----------------
__device__ __forceinline__ int swz_nwg(int orig, int nwg) {
    // bijective XCD-chunk swizzle (m204)
    const int q = nwg >> 3, r = nwg & 7;
    const int x = orig & 7, k = orig >> 3;
    return (x < r ? x * (q + 1) : r * (q + 1) + (x - r) * q) + k;
}

__device__ __forceinline__ void gl_lds16(const float* g, float* l) {
    // async 16B global->LDS; LDS dest = wave-uniform base + lane*16 (m97/m104)
    __builtin_amdgcn_global_load_lds((const __attribute__((address_space(1))) void*)g,
                                     (__attribute__((address_space(3))) void*)l,
                                     16, 0, 0);
}

#define VMCNT(n) asm volatile("s_waitcnt vmcnt(" #n ")" ::: "memory")

// staging slot -> clamped global source (100 slots: 0-59 u rows 0-5, 60-99 v rows 0-3)
__device__ __forceinline__ const float* slot_src(int s, const float* ub, const float* vb,
                                                 int base_u, int base_v, int as) {
    const bool isv = s >= 60;
    const int ss = isv ? s - 60 : s;
    const int rr = ss / 10, cg = ss - rr * 10;
    const int gb = isv ? base_v : base_u;
    const int gr = max(0, min(gb + rr, LATN - 1));
    const int gc = max(0, min(as + 4 * cg, LONN - 4));  // 16B-contiguous, in-bounds
    return (isv ? vb : ub) + ((size_t)gr * LONN + gc);
}

// vertical stencil + qg/Ucol/Vcol emission for one halo point (identical math all rounds)
__device__ __forceinline__ void emit_point(float* __restrict__ qg,
                                           float* __restrict__ Ucol, float* __restrict__ Vcol,
                                           int hidx, const float (&vo)[NLEV],
                                           float wu, float wv, float fc,
                                           float idp, float i2dp)
{
    Ucol[hidx] = wu;
    Vcol[hidx] = wv;
    float vp1m = (vo[1] - vo[0]) * idp;              // vp1[0]
    float vp1c = (vo[2] - vo[0]) * i2dp;             // vp1[1]
    qg[0 * HRHC + hidx] = vo[0] + fc + QG_COEF * ((vp1c - vp1m) * idp);
    #pragma unroll
    for (int l = 1; l < NLEV - 1; ++l) {
        const float vp1n = (l == NLEV - 2) ? (vo[NLEV-1] - vo[NLEV-2]) * idp
                                           : (vo[l+2] - vo[l]) * i2dp;   // vp1[l+1]
        qg[l * HRHC + hidx] = vo[l] + fc + QG_COEF * ((vp1n - vp1m) * i2dp);
        vp1m = vp1c; vp1c = vp1n;
    }
    qg[(NLEV-1) * HRHC + hidx] = vo[NLEV-1] + fc + QG_COEF * ((vp1c - vp1m) * idp);
}

// ---------------- fused kernel: wave-private staging rings, ZERO phase-1 barriers ----------------
__launch_bounds__(256, 4)
__global__ void pl_fused_kernel(const float* __restrict__ u, const float* __restrict__ v,
                                float* __restrict__ ws)
{
    __shared__ float stg[4 * WVFL];          // 4 waves x 3-deep ring x 400 floats = 19,200 B
    __shared__ float qg[NLEV * HRHC];        // 23,296 B
    __shared__ float uvred[2 * HRHC];        // Ucol/Vcol; reused as red[16][16]
    float* Ucol = uvred;
    float* Vcol = uvred + HRHC;
    // total LDS = 46,080 B -> 3 WG/CU

    const int tid = threadIdx.x;
    const int b  = blockIdx.y;
    const int wg = swz_nwg(blockIdx.x, NWG);
    const int rt = wg / NCT, ct = wg - rt * NCT;
    const int i0 = rt * TI, j0 = ct * TJ;

    const float* ub = u + (size_t)b * BATSTRIDE;
    const float* vb = v + (size_t)b * BATSTRIDE;

    // ---- preamble: all ws-table VMEM up front (keeps vmcnt counting exact) ----
    const float idp = ws[WS_INVDP], i2dp = ws[WS_INV2DP];
    float wlev[NLEV];
    #pragma unroll
    for (int l = 0; l < NLEV; ++l) wlev[l] = ws[WS_W + l];

    const int wid = tid >> 6, lane = tid & 63;
    const int w4 = wid * 4;                  // wave's first halo row
    const bool q1v = (wid < 3);              // wave 3 owns only 2 rows (q=0)
    const int base_u = i0 + w4 - 2;
    const int base_v = i0 + w4 - 1;
    const int as = (j0 - 2) & ~3;            // aligned staged col base

    // per-point setup: q=0 -> rows w4+(lane>>5), q=1 -> +2 (waves 0-2 only)
    int uoc[2], uop[2], uom[2], voc[2], vop_[2], vom[2], hx[2];
    float psc[2], psr[2], pfc[2];
    #pragma unroll
    for (int q = 0; q < 2; ++q) {
        const int hr = w4 + (lane >> 5) + 2 * q;
        const int hc = lane & 31;
        hx[q] = hr * HC + hc;
        const int r  = max(0, min(i0 - 1 + hr, LATN - 1));
        const int c  = max(0, min(j0 - 1 + hc, LONN - 1));
        const int rp = min(r + 1, LATN - 1), rm = max(r - 1, 0);
        const int cp = min(c + 1, LONN - 1), cm = max(c - 1, 0);
        const int urc = max(0, min(r  - base_u, UROWS - 1));
        const int urp = max(0, min(rp - base_u, UROWS - 1));
        const int urm = max(0, min(rm - base_u, UROWS - 1));
        const int vrc = max(0, min(r  - base_v, VROWS - 1));
        const int sc = c - as, sp = cp - as, sm = cm - as;
        uoc[q]  = urc * SCOLS + sc;
        uop[q]  = urp * SCOLS + sc;
        uom[q]  = urm * SCOLS + sc;
        voc[q]  = UROWS * SCOLS + vrc * SCOLS + sc;
        vop_[q] = UROWS * SCOLS + vrc * SCOLS + sp;
        vom[q]  = UROWS * SCOLS + vrc * SCOLS + sm;
        psc[q] = ((c == 0 || c == LONN - 1) ? INV_DLON : INV_2DLON) * ws[WS_INVDX + r];
        psr[q] = ((r == 0 || r == LATN - 1) ? INV_DLAT : INV_2DLAT) * INV_R;
        pfc[q] = ws[WS_FCOR + r];
    }

    // staging sources: op0 = slot lane (0-63), op1 = slot 64+lane (lanes<36)
    const float* srcA = slot_src(lane, ub, vb, base_u, base_v, as);
    const float* srcB = slot_src(min(64 + lane, 99), ub, vb, base_u, base_v, as);
    float* wbuf = &stg[wid * WVFL];

    #define STAGE(lev) do {                                                        \
        gl_lds16(srcA + (size_t)(lev) * SLICE, wbuf + ((lev) % NRING) * BUFFL);    \
        if (lane < 36)                                                             \
            gl_lds16(srcB + (size_t)(lev) * SLICE,                                 \
                     wbuf + ((lev) % NRING) * BUFFL + 256);                        \
    } while (0)

    // drain preamble VMEM so counted vmcnt below sees only staging ops
    asm volatile("s_waitcnt vmcnt(0)" ::: "memory");
    __builtin_amdgcn_sched_barrier(0);

    // ---- phase 1: wave-local counted-vmcnt pipeline, d=2 prefetch, NO barriers ----
    float vo0[NLEV], vo1[NLEV];
    float wu0 = 0.f, wv0 = 0.f, wu1 = 0.f, wv1 = 0.f;
    STAGE(0);
    STAGE(1);
    #pragma unroll
    for (int l = 0; l < NLEV; ++l) {
        if (l + 2 < NLEV) {
            __builtin_amdgcn_sched_barrier(0);   // pin: prior level's ds_reads stay before
            STAGE(l + 2);
        }
        if (l < NLEV - 2)       { VMCNT(4); }    // levels l+1,l+2 in flight (2 ops each)
        else if (l == NLEV - 2) { VMCNT(2); }
        else                    { VMCNT(0); }
        __builtin_amdgcn_sched_barrier(0);       // no ds_read hoists above the wait
        const float wl = wlev[l];
        const float* bf = &stg[wid * WVFL + (l % NRING) * BUFFL];
        vo0[l] = (bf[vop_[0]] - bf[vom[0]]) * psc[0]
               - (bf[uop[0]]  - bf[uom[0]]) * psr[0];
        wu0 = fmaf(wl, bf[uoc[0]], wu0);
        wv0 = fmaf(wl, bf[voc[0]], wv0);
        if (q1v) {
            vo1[l] = (bf[vop_[1]] - bf[vom[1]]) * psc[1]
                   - (bf[uop[1]]  - bf[uom[1]]) * psr[1];
            wu1 = fmaf(wl, bf[uoc[1]], wu1);
            wv1 = fmaf(wl, bf[voc[1]], wv1);
        }
    }
    #undef STAGE

    // ---- vertical stencil epilogue (rolling window inside emit_point, identical math) ----
    emit_point(qg, Ucol, Vcol, hx[0], vo0, wu0, wv0, pfc[0], idp, i2dp);
    if (q1v)
        emit_point(qg, Ucol, Vcol, hx[1], vo1, wu1, wv1, pfc[1], idp, i2dp);
    __syncthreads();

    // ---- phase 2: pure-LDS stencils over 360 interior points ----
    float vals[16];
    #pragma unroll
    for (int k = 0; k < 16; ++k) vals[k] = 0.f;

    for (int p = tid; p < NPTS; p += 256) {
        const int oi = p / TJ, oj = p - oi * TJ;
        const int i = i0 + oi, j = j0 + oj;
        const float mval = (i < LATN) ? 1.f : 0.f;
        const int ic = min(i, LATN - 1);
        const int hb = (oi + 1) * HC + (oj + 1);
        const float siR = ((ic == 0 || ic == LATN - 1) ? INV_DLAT : INV_2DLAT) * INV_R;
        const float sjx = ((j == 0 || j == LONN - 1) ? INV_DLON : INV_2DLON) * ws[WS_INVDX + ic];

        float ssqt = 0.f, grad = 0.f;
        #pragma unroll
        for (int l = 0; l < NLEV; ++l) {
            const int base = l * HRHC + hb;
            const float qc = qg[base] * mval;            // masked at source
            const float gl = (qg[base + HC] - qg[base - HC]) * siR;
            const float gn = (qg[base + 1]  - qg[base - 1])  * sjx;
            vals[l] += qc;
            ssqt += qc * qc;
            grad += gl * gl + gn * gn;
        }
        const float du = (Ucol[hb + 1]  - Ucol[hb - 1])  * sjx;
        const float dv = (Vcol[hb + HC] - Vcol[hb - HC]) * siR;
        const float cd = du + dv;
        vals[13] += ssqt;
        vals[14] = fmaf(mval, grad, vals[14]);
        vals[15] = fmaf(mval, cd * cd, vals[15]);
    }

    // ---- reduction: 4-step 16-lane-group butterfly + LDS transpose ----
    #pragma unroll
    for (int k = 0; k < 16; ++k) {
        float x = vals[k];
        x += __shfl_xor(x, 8, 64);
        x += __shfl_xor(x, 4, 64);
        x += __shfl_xor(x, 2, 64);
        x += __shfl_xor(x, 1, 64);
        vals[k] = x;
    }
    const int g = tid >> 4, k16 = tid & 15;
    float myv = vals[0];
    #pragma unroll
    for (int k = 1; k < 16; ++k) if (k16 == k) myv = vals[k];   // static-index select

    __syncthreads();                         // Ucol/Vcol reads done -> reuse as red
    float (*red)[16] = (float (*)[16])uvred;
    red[g][k16] = myv;
    __syncthreads();

    if (tid < 16) {
        const int k = tid;
        float s = 0.f;
        #pragma unroll
        for (int g2 = 0; g2 < 16; ++g2) s += red[g2][k];
        int target;
        if (k < 13)       target = ACC_SUM + b * 13 + k;
        else if (k == 13) target = ACC_SSQ + b;
        else if (k == 14) target = ACC_GRAD;
        else              target = ACC_MASS;
        const int bank = (b * NWG + blockIdx.x) & (NBANK - 1);
        atomicAdd(&ws[WS_ACC + bank * BANKSTRIDE + target], s);
    }
}

// ---------------- finalize: sum banks, apply formulas ----------------
__global__ void pl_finalize_kernel(const float* __restrict__ ws, float* __restrict__ out) {
    __shared__ float tot[N_ACC];
    const int t = threadIdx.x;
    if (t < N_ACC) {
        float s = 0.f;
        for (int bk = 0; bk < NBANK; ++bk) s += ws[WS_ACC + bk * BANKSTRIDE + t];
        tot[t] = s;
    }
    __syncthreads();
    if (t == 0) {
        const float N = (float)SLICE;
        float s2 = 0.f;
        for (int s = 0; s < 2 * NLEV; ++s) s2 += tot[ACC_SUM + s] * tot[ACC_SUM + s];
        const float ssq = tot[ACC_SSQ + 0] + tot[ACC_SSQ + 1];
        float vmean = (ssq - s2 / N) / (N - 1.0f) * (1.0f / (2.0f * NLEV));
        float gmean = tot[ACC_GRAD] / (float)(NBATCH * NLEV * SLICE);
        float mmean = tot[ACC_MASS] / (float)(NBATCH * SLICE);
        out[0] = vmean + 0.1f * gmean + mmean;          // spectra_loss statically 0
    }
}

extern "C" void kernel_launch(void* const* d_in, const int* in_sizes, int n_in,
                              void* d_out, int out_size, void* d_ws, size_t ws_size,
                              hipStream_t stream) {
    const float* u    = (const float*)d_in[0];
    const float* v    = (const float*)d_in[1];
    const float* plev = (const float*)d_in[2];
    float* ws  = (float*)d_ws;
    float* out = (float*)d_out;

    hipLaunchKernelGGL(pl_setup_kernel, dim3(1), dim3(1024), 0, stream, plev, ws);
    hipLaunchKernelGGL(pl_fused_kernel, dim3(NWG, NBATCH), dim3(256), 0, stream, u, v, ws);
    hipLaunchKernelGGL(pl_finalize_kernel, dim3(1), dim3(64), 0, stream, ws, out);
}

// Round 7
// 76.041 us; speedup vs baseline: 1.9664x; 1.2904x over previous
//
#include <hip/hip_runtime.h>
#include <math.h>

#define LATN 721
#define LONN 1440
#define NLEV 13
#define NBATCH 2
#define SLICE (LATN * LONN)              // 1,038,240
#define BATSTRIDE (NLEV * SLICE)

// row-streaming geometry: wave = 64 cols (62 outputs + 2 halo lanes)
#define SEGS 6
#define OUTW 62                          // outputs per wave
#define WGOUT 248                        // outputs per WG (4 waves)
#define NWGX (LATN * SEGS)               // 4326

// ---- ws float layout ----
#define NBANK      128
#define BANKSTRIDE 64
#define WS_ACC     0                     // [NBANK*BANKSTRIDE]
#define ACC_SUM    0        // [26] per (b,l) sums
#define ACC_SSQ    26       // [2]  per-batch total sum-of-squares
#define ACC_GRAD   28
#define ACC_MASS   29
#define N_ACC      30
#define WS_INVDX   (NBANK * BANKSTRIDE)          // [721]
#define WS_FCOR    (WS_INVDX + LATN)             // [721]
#define WS_W       (WS_FCOR + LATN)              // [13]
#define WS_INVDP   (WS_W + NLEV)
#define WS_INV2DP  (WS_INVDP + 1)

constexpr float INV_R     = (float)(1.0 / 6371000.0);
constexpr float INV_DLAT  = (float)(720.0 / M_PI);
constexpr float INV_2DLAT = (float)(360.0 / M_PI);
constexpr float INV_DLON  = (float)(1440.0 / (2.0 * M_PI));
constexpr float INV_2DLON = (float)(720.0 / (2.0 * M_PI));
constexpr float QG_COEF   = 1e-4f;   // F0^2 / N^2

// ---------------- setup: row tables, weights, zero accumulators ----------------
__global__ void pl_setup_kernel(const float* __restrict__ plev, float* __restrict__ ws) {
    const int t = threadIdx.x;
    if (t < LATN) {
        double lat;
        if (t == 0)            lat = (double)(-(float)(M_PI / 2.0));
        else if (t == LATN-1)  lat = (double)( (float)(M_PI / 2.0));
        else                   lat = (double)((float)(-M_PI / 2.0 + (double)t * (M_PI / 720.0)));
        double c = cos(lat);
        if (c < 1e-8) c = 1e-8;                      // matches jnp.clip(cos, 1e-8)
        ws[WS_INVDX + t] = (float)(1.0 / (6371000.0 * c));
        ws[WS_FCOR  + t] = (float)(2.0 * 7.292e-05 * sin(lat));
    }
    if (t < NLEV) {
        float p[NLEV];
        #pragma unroll
        for (int l = 0; l < NLEV; ++l) p[l] = plev[l] * 100.0f;
        float dpl[NLEV-1];
        #pragma unroll
        for (int l = 0; l < NLEV-1; ++l) dpl[l] = p[l+1] - p[l];
        float raw;
        if (t == 0)            raw = dpl[0] * 0.5f;
        else if (t == NLEV-1)  raw = dpl[NLEV-2] * 0.5f;
        else                   raw = (dpl[t-1] + dpl[t]) * 0.5f;
        float s = dpl[0] * 0.5f + dpl[NLEV-2] * 0.5f;
        #pragma unroll
        for (int l = 1; l < NLEV-1; ++l) s += (dpl[l-1] + dpl[l]) * 0.5f;
        if (s < 1e-8f) s = 1e-8f;
        ws[WS_W + t] = raw / s;
    }
    if (t == 0) {
        float sd = 0.f;
        for (int l = 0; l < NLEV-1; ++l) sd += plev[l+1] - plev[l];
        float dp = sd / (float)(NLEV-1) * 100.0f;    // mean(diff)*100 (hPa->Pa)
        ws[WS_INVDP]  = 1.0f / dp;
        ws[WS_INV2DP] = 1.0f / (2.0f * dp);
    }
    for (int z = t; z < NBANK * BANKSTRIDE; z += 1024) ws[WS_ACC + z] = 0.0f;
}

// ---------------- helpers ----------------
__device__ __forceinline__ int swz_nwg(int orig, int nwg) {
    // bijective XCD-chunk swizzle (m204)
    const int q = nwg >> 3, r = nwg & 7;
    const int x = orig & 7, k = orig >> 3;
    return (x < r ? x * (q + 1) : r * (q + 1) + (x - r) * q) + k;
}

// ---------------- row-streaming fused kernel: no staging LDS, no barriers ----------------
// thread = one (row,col) point, all levels; 3-row qg recompute; shfl for col neighbors
__launch_bounds__(256)
__global__ void pl_row_kernel(const float* __restrict__ u, const float* __restrict__ v,
                              float* __restrict__ ws)
{
    __shared__ float red[16][17];

    const int tid  = threadIdx.x;
    const int lane = tid & 63, w = tid >> 6;
    const int b  = blockIdx.y;
    const int wg = swz_nwg(blockIdx.x, NWGX);
    const int r   = wg / SEGS, seg = wg - r * SEGS;

    const int c_un = seg * WGOUT + w * OUTW + lane - 1;   // lane 0 / 63 are shfl halo
    const int c  = max(0, min(c_un, LONN - 1));
    const float mval = (lane >= 1 && lane <= 62 && c_un < LONN) ? 1.f : 0.f;

    const int rm1 = max(r - 1, 0), rp1 = min(r + 1, LATN - 1);
    const int rm2 = max(r - 2, 0), rp2 = min(r + 2, LATN - 1);
    const int cLo = max(c - 1, 0), cRi = min(c + 1, LONN - 1);
    const bool rTop = (r == 0), rBot = (r == LATN - 1);

    const float* ub = u + (size_t)b * BATSTRIDE;
    const float* vb = v + (size_t)b * BATSTRIDE;

    const float idp = ws[WS_INVDP], i2dp = ws[WS_INV2DP];
    const float invdx_m = ws[WS_INVDX + rm1];
    const float invdx_c = ws[WS_INVDX + r];
    const float invdx_p = ws[WS_INVDX + rp1];
    const float fc_m = ws[WS_FCOR + rm1];
    const float fc_c = ws[WS_FCOR + r];
    const float fc_p = ws[WS_FCOR + rp1];

    const float eC   = (c == 0 || c == LONN - 1) ? INV_DLON : INV_2DLON;
    const float sc_m = eC * invdx_m, sc_c = eC * invdx_c, sc_p = eC * invdx_p;
    const float sr_c = ((r   == 0 || r   == LATN - 1) ? INV_DLAT : INV_2DLAT) * INV_R;
    const float sr_m = ((rm1 == 0)                    ? INV_DLAT : INV_2DLAT) * INV_R;
    const float sr_p = ((rp1 == LATN - 1)             ? INV_DLAT : INV_2DLAT) * INV_R;
    const float siR = sr_c;          // grad_lat / dv-dy scale at row r
    const float sjx = sc_c;          // grad_lon / du-dx scale at (r,c)

    // per-lane element offsets (level advance = uniform SGPR pointer bump)
    const int o_um2 = rm2 * LONN + c;
    const int o_um1 = rm1 * LONN + c;
    const int o_u0  = r   * LONN + c;
    const int o_up1 = rp1 * LONN + c;
    const int o_up2 = rp2 * LONN + c;
    const int o_v0L = r   * LONN + cLo;
    const int o_v0R = r   * LONN + cRi;

    // ---- LOOP1: 10 coalesced loads/level -> vort for rows r-1, r, r+1 (regs) ----
    float vo_m[NLEV], vo_c[NLEV], vo_p[NLEV];
    float wu = 0.f, wvm = 0.f, wvp = 0.f;
    const float* up = ub;
    const float* vp = vb;
    #pragma unroll
    for (int l = 0; l < NLEV; ++l) {
        const float wl  = ws[WS_W + l];                  // uniform -> SGPR
        const float um2 = up[o_um2], um1 = up[o_um1], u0 = up[o_u0];
        const float up1 = up[o_up1], up2 = up[o_up2];
        const float vm1 = vp[o_um1], v00 = vp[o_u0], vp1 = vp[o_up1];
        const float v0L = vp[o_v0L], v0R = vp[o_v0R];
        // c+-1 of rows r+-1 via lane shuffles (halo lanes masked downstream)
        const float vm1L = __shfl_up(vm1, 1), vm1R = __shfl_down(vm1, 1);
        const float vp1L = __shfl_up(vp1, 1), vp1R = __shfl_down(vp1, 1);
        const float vc  = (v0R  - v0L)  * sc_c - (up1 - um1) * sr_c;
        const float vm  = (vm1R - vm1L) * sc_m - (u0  - um2) * sr_m;
        const float vpv = (vp1R - vp1L) * sc_p - (up2 - u0)  * sr_p;
        vo_c[l] = vc;
        vo_m[l] = rTop ? vc : vm;                        // clamped halo row == own row
        vo_p[l] = rBot ? vc : vpv;
        wu  = fmaf(wl, u0,  wu);                         // Ucol[r][c]
        wvm = fmaf(wl, vm1, wvm);                        // Vcol[r-1][c]
        wvp = fmaf(wl, vp1, wvp);                        // Vcol[r+1][c]
        up += SLICE; vp += SLICE;                        // SALU bump
    }

    // ---- LOOP2: rolling vertical stencil (3 rows) + consume qg per level ----
    float vals[16];
    #pragma unroll
    for (int k = 0; k < 16; ++k) vals[k] = 0.f;
    float ssqt = 0.f, grad = 0.f;

    auto consume = [&](int l, float qgm, float qgc, float qgp) {
        const float qcm = qgc * mval;
        vals[l] += qcm;
        ssqt += qcm * qcm;
        const float gl  = (qgp - qgm) * siR;
        const float qgL = __shfl_up(qgc, 1), qgR = __shfl_down(qgc, 1);
        const float gn  = (qgR - qgL) * sjx;
        grad += gl * gl + gn * gn;
    };

    float am_ = (vo_m[1] - vo_m[0]) * idp, ac_ = (vo_m[2] - vo_m[0]) * i2dp;
    float bm_ = (vo_c[1] - vo_c[0]) * idp, bc_ = (vo_c[2] - vo_c[0]) * i2dp;
    float cm_ = (vo_p[1] - vo_p[0]) * idp, cc_ = (vo_p[2] - vo_p[0]) * i2dp;
    consume(0, vo_m[0] + fc_m + QG_COEF * ((ac_ - am_) * idp),
               vo_c[0] + fc_c + QG_COEF * ((bc_ - bm_) * idp),
               vo_p[0] + fc_p + QG_COEF * ((cc_ - cm_) * idp));
    #pragma unroll
    for (int l = 1; l < NLEV - 1; ++l) {
        const float an = (l == NLEV - 2) ? (vo_m[NLEV-1] - vo_m[NLEV-2]) * idp
                                         : (vo_m[l+2] - vo_m[l]) * i2dp;
        const float bn = (l == NLEV - 2) ? (vo_c[NLEV-1] - vo_c[NLEV-2]) * idp
                                         : (vo_c[l+2] - vo_c[l]) * i2dp;
        const float cn = (l == NLEV - 2) ? (vo_p[NLEV-1] - vo_p[NLEV-2]) * idp
                                         : (vo_p[l+2] - vo_p[l]) * i2dp;
        consume(l, vo_m[l] + fc_m + QG_COEF * ((an - am_) * i2dp),
                   vo_c[l] + fc_c + QG_COEF * ((bn - bm_) * i2dp),
                   vo_p[l] + fc_p + QG_COEF * ((cn - cm_) * i2dp));
        am_ = ac_; ac_ = an;
        bm_ = bc_; bc_ = bn;
        cm_ = cc_; cc_ = cn;
    }
    consume(NLEV - 1, vo_m[NLEV-1] + fc_m + QG_COEF * ((ac_ - am_) * idp),
                      vo_c[NLEV-1] + fc_c + QG_COEF * ((bc_ - bm_) * idp),
                      vo_p[NLEV-1] + fc_p + QG_COEF * ((cc_ - cm_) * idp));

    vals[13] += ssqt;
    vals[14] = fmaf(mval, grad, vals[14]);
    // mass: du/dx via Ucol lane-shfl; dv/dy from in-thread Vcol[r+-1]
    const float uR = __shfl_down(wu, 1), uL = __shfl_up(wu, 1);
    const float cd = (uR - uL) * sjx + (wvp - wvm) * siR;
    vals[15] = fmaf(mval, cd * cd, vals[15]);

    // ---- reduction: 4-step 16-lane-group butterfly + LDS transpose (16 values) ----
    #pragma unroll
    for (int k = 0; k < 16; ++k) {
        float x = vals[k];
        x += __shfl_xor(x, 8, 64);
        x += __shfl_xor(x, 4, 64);
        x += __shfl_xor(x, 2, 64);
        x += __shfl_xor(x, 1, 64);
        vals[k] = x;
    }
    const int g = tid >> 4, k16 = tid & 15;
    float myv = vals[0];
    #pragma unroll
    for (int k = 1; k < 16; ++k) if (k16 == k) myv = vals[k];   // static-index select
    red[g][k16] = myv;
    __syncthreads();

    if (tid < 16) {
        const int k = tid;
        float s = 0.f;
        #pragma unroll
        for (int g2 = 0; g2 < 16; ++g2) s += red[g2][k];
        int target;
        if (k < 13)       target = ACC_SUM + b * 13 + k;
        else if (k == 13) target = ACC_SSQ + b;
        else if (k == 14) target = ACC_GRAD;
        else              target = ACC_MASS;
        const int bank = (b * NWGX + blockIdx.x) & (NBANK - 1);
        atomicAdd(&ws[WS_ACC + bank * BANKSTRIDE + target], s);
    }
}

// ---------------- finalize: sum banks, apply formulas ----------------
__global__ void pl_finalize_kernel(const float* __restrict__ ws, float* __restrict__ out) {
    __shared__ float tot[N_ACC];
    const int t = threadIdx.x;
    if (t < N_ACC) {
        float s = 0.f;
        for (int bk = 0; bk < NBANK; ++bk) s += ws[WS_ACC + bk * BANKSTRIDE + t];
        tot[t] = s;
    }
    __syncthreads();
    if (t == 0) {
        const float N = (float)SLICE;
        float s2 = 0.f;
        for (int s = 0; s < 2 * NLEV; ++s) s2 += tot[ACC_SUM + s] * tot[ACC_SUM + s];
        const float ssq = tot[ACC_SSQ + 0] + tot[ACC_SSQ + 1];
        float vmean = (ssq - s2 / N) / (N - 1.0f) * (1.0f / (2.0f * NLEV));
        float gmean = tot[ACC_GRAD] / (float)(NBATCH * NLEV * SLICE);
        float mmean = tot[ACC_MASS] / (float)(NBATCH * SLICE);
        out[0] = vmean + 0.1f * gmean + mmean;          // spectra_loss statically 0
    }
}

extern "C" void kernel_launch(void* const* d_in, const int* in_sizes, int n_in,
                              void* d_out, int out_size, void* d_ws, size_t ws_size,
                              hipStream_t stream) {
    const float* u    = (const float*)d_in[0];
    const float* v    = (const float*)d_in[1];
    const float* plev = (const float*)d_in[2];
    float* ws  = (float*)d_ws;
    float* out = (float*)d_out;

    hipLaunchKernelGGL(pl_setup_kernel, dim3(1), dim3(1024), 0, stream, plev, ws);
    hipLaunchKernelGGL(pl_row_kernel, dim3(NWGX, NBATCH), dim3(256), 0, stream, u, v, ws);
    hipLaunchKernelGGL(pl_finalize_kernel, dim3(1), dim3(64), 0, stream, ws, out);
}